// Round 1
// baseline (1043.523 us; speedup 1.0000x reference)
//
#include <hip/hip_runtime.h>

#define F_IN 512
#define HDIM 64

// wsum[k] = sum_j linW[j][k]; wsum[64] = sum_j linB[j]
__global__ void prep_kernel(const float* __restrict__ linW,
                            const float* __restrict__ linB,
                            float* __restrict__ wsum) {
    int k = threadIdx.x;
    float s = 0.f;
    for (int j = 0; j < HDIM; ++j) s += linW[j * HDIM + k];
    wsum[k] = s;
    if (k == 0) {
        float b = 0.f;
        for (int j = 0; j < HDIM; ++j) b += linB[j];
        wsum[HDIM] = b;
    }
}

__global__ void zero_kernel(float* __restrict__ p, int n) {
    int i = blockIdx.x * blockDim.x + threadIdx.x;
    if (i < n) p[i] = 0.f;
}

// H[n][j] = sum_k X[n][k] * W[j][k]   X:[n_nodes,512] W:[64,512] H:[n_nodes,64]
// 64x64 output tile per block, 256 threads, each thread 4x4 outputs.
__global__ __launch_bounds__(256) void gemm_kernel(const float* __restrict__ X,
                                                   const float* __restrict__ W,
                                                   float* __restrict__ H,
                                                   int n_nodes) {
    __shared__ float sX[64][33];   // +1 pad breaks bank conflicts
    __shared__ float sW[64][33];
    const int t = threadIdx.x;
    const int m0 = blockIdx.x * 64;
    const int tx = t & 15;   // feature group: features tx*4..tx*4+3
    const int ty = t >> 4;   // node group:    nodes   ty*4..ty*4+3
    float acc[4][4] = {};

    for (int k0 = 0; k0 < F_IN; k0 += 32) {
#pragma unroll
        for (int r = 0; r < 2; ++r) {
            int q = t + 256 * r;          // 0..511 -> 64 rows x 8 float4
            int rowi = q >> 3;            // 0..63
            int kk = (q & 7) << 2;        // 0,4,...,28
            int gm = m0 + rowi;
            if (gm >= n_nodes) gm = n_nodes - 1;  // clamp (stores guarded)
            float4 xv = *reinterpret_cast<const float4*>(&X[(size_t)gm * F_IN + k0 + kk]);
            sX[rowi][kk + 0] = xv.x; sX[rowi][kk + 1] = xv.y;
            sX[rowi][kk + 2] = xv.z; sX[rowi][kk + 3] = xv.w;
            float4 wv = *reinterpret_cast<const float4*>(&W[(size_t)rowi * F_IN + k0 + kk]);
            sW[rowi][kk + 0] = wv.x; sW[rowi][kk + 1] = wv.y;
            sW[rowi][kk + 2] = wv.z; sW[rowi][kk + 3] = wv.w;
        }
        __syncthreads();
#pragma unroll
        for (int kk = 0; kk < 32; ++kk) {
            float xr[4], wr[4];
#pragma unroll
            for (int i = 0; i < 4; ++i) xr[i] = sX[ty * 4 + i][kk];
#pragma unroll
            for (int j = 0; j < 4; ++j) wr[j] = sW[tx * 4 + j][kk];
#pragma unroll
            for (int i = 0; i < 4; ++i)
#pragma unroll
                for (int j = 0; j < 4; ++j)
                    acc[i][j] += xr[i] * wr[j];
        }
        __syncthreads();
    }

#pragma unroll
    for (int i = 0; i < 4; ++i) {
        int gm = m0 + ty * 4 + i;
        if (gm < n_nodes) {
#pragma unroll
            for (int j = 0; j < 4; ++j)
                H[(size_t)gm * HDIM + tx * 4 + j] = acc[i][j];
        }
    }
}

// agg[row[e]][j] += w[e] * h[col[e]][j]; one 64-lane wave per edge, 4 edges/block
__global__ __launch_bounds__(256) void scatter_kernel(const int* __restrict__ row,
                                                      const int* __restrict__ col,
                                                      const float* __restrict__ w,
                                                      const float* __restrict__ h,
                                                      float* __restrict__ agg,
                                                      int n_edges) {
    const int lane = threadIdx.x & 63;
    const int grp = threadIdx.x >> 6;
    const int e = blockIdx.x * 4 + grp;
    if (e >= n_edges) return;
    const int r = row[e];
    const int c = col[e];
    const float we = w[e];
    atomicAdd(&agg[(size_t)r * HDIM + lane], we * h[(size_t)c * HDIM + lane]);
}

// z[n] = sum_j prelu(agg[n][j] + gbias[j]) * wsum[j] + wsum[64]
__global__ __launch_bounds__(256) void finalize_kernel(const float* __restrict__ agg,
                                                       const float* __restrict__ gbias,
                                                       const float* __restrict__ wsum,
                                                       const float* __restrict__ prelu_a,
                                                       float* __restrict__ z,
                                                       int n_nodes) {
    const int lane = threadIdx.x & 63;
    const int wv = threadIdx.x >> 6;
    const int n = blockIdx.x * 4 + wv;
    if (n >= n_nodes) return;
    const float a = prelu_a[0];
    float v = agg[(size_t)n * HDIM + lane] + gbias[lane];
    v = (v >= 0.f) ? v : a * v;
    float p = v * wsum[lane];
#pragma unroll
    for (int m = 32; m >= 1; m >>= 1) p += __shfl_xor(p, m, 64);
    if (lane == 0) z[n] = p + wsum[HDIM];
}

extern "C" void kernel_launch(void* const* d_in, const int* in_sizes, int n_in,
                              void* d_out, int out_size, void* d_ws, size_t ws_size,
                              hipStream_t stream) {
    const float* x1    = (const float*)d_in[0];
    const float* x2    = (const float*)d_in[1];
    const int*   erow  = (const int*)d_in[2];
    const int*   ecol  = (const int*)d_in[3];
    const float* ew    = (const float*)d_in[4];
    const float* fcw   = (const float*)d_in[5];
    const float* gbias = (const float*)d_in[6];
    const float* pa    = (const float*)d_in[7];
    const float* linw  = (const float*)d_in[8];
    const float* linb  = (const float*)d_in[9];
    float* out = (float*)d_out;

    const int n_nodes = in_sizes[0] / F_IN;   // 100000
    const int n_edges = in_sizes[2];          // 1600000

    float* h    = (float*)d_ws;                         // n_nodes*64 floats
    float* agg  = h + (size_t)n_nodes * HDIM;           // n_nodes*64 floats
    float* wsum = agg + (size_t)n_nodes * HDIM;         // 65 floats

    prep_kernel<<<1, 64, 0, stream>>>(linw, linb, wsum);

    const int gemm_grid = (n_nodes + 63) / 64;
    const int zero_grid = (n_nodes * HDIM + 255) / 256;
    const int scat_grid = (n_edges + 3) / 4;
    const int fin_grid  = (n_nodes + 3) / 4;

    const float* xs[2] = {x1, x2};
    for (int s = 0; s < 2; ++s) {
        gemm_kernel<<<gemm_grid, 256, 0, stream>>>(xs[s], fcw, h, n_nodes);
        zero_kernel<<<zero_grid, 256, 0, stream>>>(agg, n_nodes * HDIM);
        scatter_kernel<<<scat_grid, 256, 0, stream>>>(erow, ecol, ew, h, agg, n_edges);
        finalize_kernel<<<fin_grid, 256, 0, stream>>>(agg, gbias, wsum, pa,
                                                      out + (size_t)s * n_nodes, n_nodes);
    }
}

// Round 2
// 581.289 us; speedup vs baseline: 1.7952x; 1.7952x over previous
//
#include <hip/hip_runtime.h>

#define F_IN 512
#define HDIM 64

// wsum[k] = sum_j linW[j][k]; wsum[64] = sum_j linB[j]
__global__ void prep_kernel(const float* __restrict__ linW,
                            const float* __restrict__ linB,
                            float* __restrict__ wsum) {
    int k = threadIdx.x;
    float s = 0.f;
    for (int j = 0; j < HDIM; ++j) s += linW[j * HDIM + k];
    wsum[k] = s;
    if (k == 0) {
        float b = 0.f;
        for (int j = 0; j < HDIM; ++j) b += linB[j];
        wsum[HDIM] = b;
    }
}

__global__ void zero_int_kernel(int* __restrict__ p, int n) {
    int i = blockIdx.x * blockDim.x + threadIdx.x;
    if (i < n) p[i] = 0;
}

// cnt[row[e]]++
__global__ __launch_bounds__(256) void hist_kernel(const int* __restrict__ row,
                                                   int* __restrict__ cnt, int n_edges) {
    int e = blockIdx.x * blockDim.x + threadIdx.x;
    if (e < n_edges) atomicAdd(&cnt[row[e]], 1);
}

// per-block exclusive scan of cnt -> scn; block totals -> partials
__global__ __launch_bounds__(256) void scan1_kernel(const int* __restrict__ cnt,
                                                    int* __restrict__ scn,
                                                    int* __restrict__ partials, int n) {
    __shared__ int s[256];
    const int t = threadIdx.x;
    const int i = blockIdx.x * 256 + t;
    int v = (i < n) ? cnt[i] : 0;
    s[t] = v;
    __syncthreads();
#pragma unroll
    for (int off = 1; off < 256; off <<= 1) {
        int x = (t >= off) ? s[t - off] : 0;
        __syncthreads();
        s[t] += x;
        __syncthreads();
    }
    if (i < n) scn[i] = s[t] - v;           // exclusive
    if (t == 255) partials[blockIdx.x] = s[255];
}

// single-block exclusive scan of partials (P <= 512) -> poff
__global__ __launch_bounds__(512) void scan2_kernel(const int* __restrict__ partials,
                                                    int* __restrict__ poff, int P) {
    __shared__ int s[512];
    const int t = threadIdx.x;
    int v = (t < P) ? partials[t] : 0;
    s[t] = v;
    __syncthreads();
#pragma unroll
    for (int off = 1; off < 512; off <<= 1) {
        int x = (t >= off) ? s[t - off] : 0;
        __syncthreads();
        s[t] += x;
        __syncthreads();
    }
    if (t < P) poff[t] = s[t] - v;
}

// ptr[i] = scn[i] + poff[block(i)]; cursor = ptr; ptr[n] = n_edges
__global__ __launch_bounds__(256) void scan3_kernel(const int* __restrict__ scn,
                                                    const int* __restrict__ poff,
                                                    int* __restrict__ ptr,
                                                    int* __restrict__ cursor,
                                                    int n, int n_edges) {
    int i = blockIdx.x * 256 + threadIdx.x;
    if (i < n) {
        int p = scn[i] + poff[i >> 8];
        ptr[i] = p;
        cursor[i] = p;
    }
    if (i == 0) ptr[n] = n_edges;
}

// ecsr[pos] = {col, bits(weight)} at pos = cursor[row]++
__global__ __launch_bounds__(256) void fill_kernel(const int* __restrict__ row,
                                                   const int* __restrict__ col,
                                                   const float* __restrict__ w,
                                                   int* __restrict__ cursor,
                                                   int2* __restrict__ ecsr, int n_edges) {
    int e = blockIdx.x * blockDim.x + threadIdx.x;
    if (e >= n_edges) return;
    int p = atomicAdd(&cursor[row[e]], 1);
    ecsr[p] = make_int2(col[e], __float_as_int(w[e]));
}

// H[n][j] = sum_k X[n][k] * W[j][k]; 64x64 tile, transposed LDS, float4 reads
__global__ __launch_bounds__(256) void gemm_kernel(const float* __restrict__ X,
                                                   const float* __restrict__ W,
                                                   float* __restrict__ H,
                                                   int n_nodes) {
    __shared__ float sXt[32][72];   // [k][node], stride 72 floats: conflict-free
    __shared__ float sWt[32][72];   // [k][feat]
    const int t = threadIdx.x;
    const int m0 = blockIdx.x * 64;
    const int tx = t & 15;   // feature group
    const int ty = t >> 4;   // node group
    float acc[4][4] = {};

    for (int k0 = 0; k0 < F_IN; k0 += 32) {
#pragma unroll
        for (int r = 0; r < 2; ++r) {
            int q = t + 256 * r;          // 0..511 -> 64 rows x 8 float4
            int rowi = q >> 3;            // 0..63
            int kk = (q & 7) << 2;        // 0,4,...,28
            int gm = m0 + rowi;
            if (gm >= n_nodes) gm = n_nodes - 1;  // clamp (stores guarded)
            float4 xv = *reinterpret_cast<const float4*>(&X[(size_t)gm * F_IN + k0 + kk]);
            sXt[kk + 0][rowi] = xv.x; sXt[kk + 1][rowi] = xv.y;
            sXt[kk + 2][rowi] = xv.z; sXt[kk + 3][rowi] = xv.w;
            float4 wv = *reinterpret_cast<const float4*>(&W[(size_t)rowi * F_IN + k0 + kk]);
            sWt[kk + 0][rowi] = wv.x; sWt[kk + 1][rowi] = wv.y;
            sWt[kk + 2][rowi] = wv.z; sWt[kk + 3][rowi] = wv.w;
        }
        __syncthreads();
#pragma unroll
        for (int kk = 0; kk < 32; ++kk) {
            float4 xr = *reinterpret_cast<const float4*>(&sXt[kk][ty * 4]);
            float4 wr = *reinterpret_cast<const float4*>(&sWt[kk][tx * 4]);
            float xa[4] = {xr.x, xr.y, xr.z, xr.w};
            float wa[4] = {wr.x, wr.y, wr.z, wr.w};
#pragma unroll
            for (int i = 0; i < 4; ++i)
#pragma unroll
                for (int j = 0; j < 4; ++j)
                    acc[i][j] = fmaf(xa[i], wa[j], acc[i][j]);
        }
        __syncthreads();
    }

#pragma unroll
    for (int i = 0; i < 4; ++i) {
        int gm = m0 + ty * 4 + i;
        if (gm < n_nodes) {
#pragma unroll
            for (int j = 0; j < 4; ++j)
                H[(size_t)gm * HDIM + tx * 4 + j] = acc[i][j];
        }
    }
}

// fused: per node, gather-aggregate over CSR edges + bias + PReLU + wsum-dot -> z[n]
__global__ __launch_bounds__(256) void agg_finalize_kernel(const int* __restrict__ ptr,
                                                           const int2* __restrict__ ecsr,
                                                           const float* __restrict__ h,
                                                           const float* __restrict__ gbias,
                                                           const float* __restrict__ wsum,
                                                           const float* __restrict__ prelu_a,
                                                           float* __restrict__ z,
                                                           int n_nodes) {
    const int lane = threadIdx.x & 63;
    const int wv = threadIdx.x >> 6;
    const int n = blockIdx.x * 4 + wv;
    if (n >= n_nodes) return;
    const int p0 = __builtin_amdgcn_readfirstlane(ptr[n]);
    const int p1 = __builtin_amdgcn_readfirstlane(ptr[n + 1]);
    float acc = 0.f;
    int i = p0;
    for (; i + 1 < p1; i += 2) {    // 2-way unroll: overlap the dependent load pairs
        int2 e0 = ecsr[i];
        int2 e1 = ecsr[i + 1];
        float h0 = h[(size_t)e0.x * HDIM + lane];
        float h1 = h[(size_t)e1.x * HDIM + lane];
        acc = fmaf(__int_as_float(e0.y), h0, acc);
        acc = fmaf(__int_as_float(e1.y), h1, acc);
    }
    if (i < p1) {
        int2 e0 = ecsr[i];
        acc = fmaf(__int_as_float(e0.y), h[(size_t)e0.x * HDIM + lane], acc);
    }
    float v = acc + gbias[lane];
    const float a = prelu_a[0];
    v = (v >= 0.f) ? v : a * v;
    float p = v * wsum[lane];
#pragma unroll
    for (int m = 32; m >= 1; m >>= 1) p += __shfl_xor(p, m, 64);
    if (lane == 0) z[n] = p + wsum[HDIM];
}

extern "C" void kernel_launch(void* const* d_in, const int* in_sizes, int n_in,
                              void* d_out, int out_size, void* d_ws, size_t ws_size,
                              hipStream_t stream) {
    const float* x1    = (const float*)d_in[0];
    const float* x2    = (const float*)d_in[1];
    const int*   erow  = (const int*)d_in[2];
    const int*   ecol  = (const int*)d_in[3];
    const float* ew    = (const float*)d_in[4];
    const float* fcw   = (const float*)d_in[5];
    const float* gbias = (const float*)d_in[6];
    const float* pa    = (const float*)d_in[7];
    const float* linw  = (const float*)d_in[8];
    const float* linb  = (const float*)d_in[9];
    float* out = (float*)d_out;

    const int n_nodes = in_sizes[0] / F_IN;   // 100000
    const int n_edges = in_sizes[2];          // 1600000
    const int NB1 = (n_nodes + 255) / 256;    // scan blocks (<=512)

    // workspace layout
    float* h      = (float*)d_ws;                               // n_nodes*64 f32
    int2*  ecsr   = (int2*)(h + (size_t)n_nodes * HDIM);        // n_edges int2
    int*   cnt    = (int*)(ecsr + n_edges);                     // n_nodes
    int*   scn    = cnt + n_nodes;                              // n_nodes
    int*   ptr    = scn + n_nodes;                              // n_nodes+1
    int*   cursor = ptr + n_nodes + 1;                          // n_nodes
    int*   partials = cursor + n_nodes;                         // NB1
    int*   poff   = partials + NB1;                             // NB1
    float* wsum   = (float*)(poff + NB1);                       // 65 f32

    const int gN   = (n_nodes + 255) / 256;
    const int gE   = (n_edges + 255) / 256;
    const int gemm_grid = (n_nodes + 63) / 64;
    const int fin_grid  = (n_nodes + 3) / 4;

    prep_kernel<<<1, 64, 0, stream>>>(linw, linb, wsum);

    // CSR build (edges shared by both inputs -> build once per call)
    zero_int_kernel<<<gN, 256, 0, stream>>>(cnt, n_nodes);
    hist_kernel<<<gE, 256, 0, stream>>>(erow, cnt, n_edges);
    scan1_kernel<<<NB1, 256, 0, stream>>>(cnt, scn, partials, n_nodes);
    scan2_kernel<<<1, 512, 0, stream>>>(partials, poff, NB1);
    scan3_kernel<<<gN, 256, 0, stream>>>(scn, poff, ptr, cursor, n_nodes, n_edges);
    fill_kernel<<<gE, 256, 0, stream>>>(erow, ecol, ew, cursor, ecsr, n_edges);

    const float* xs[2] = {x1, x2};
    for (int s = 0; s < 2; ++s) {
        gemm_kernel<<<gemm_grid, 256, 0, stream>>>(xs[s], fcw, h, n_nodes);
        agg_finalize_kernel<<<fin_grid, 256, 0, stream>>>(ptr, ecsr, h, gbias, wsum, pa,
                                                          out + (size_t)s * n_nodes, n_nodes);
    }
}

// Round 3
// 447.917 us; speedup vs baseline: 2.3297x; 1.2978x over previous
//
#include <hip/hip_runtime.h>

#define F_IN 512
#define HDIM 64

typedef _Float16 f16;
typedef _Float16 f16x8 __attribute__((ext_vector_type(8)));
typedef float f32x4 __attribute__((ext_vector_type(4)));

// wsum[k] = sum_j linW[j][k]; wsum[64] = sum_j linB[j]
__global__ void prep_kernel(const float* __restrict__ linW,
                            const float* __restrict__ linB,
                            float* __restrict__ wsum) {
    int k = threadIdx.x;
    float s = 0.f;
    for (int j = 0; j < HDIM; ++j) s += linW[j * HDIM + k];
    wsum[k] = s;
    if (k == 0) {
        float b = 0.f;
        for (int j = 0; j < HDIM; ++j) b += linB[j];
        wsum[HDIM] = b;
    }
}

// Lay out fc_weight as f16 in exact B-fragment order:
// wf[((s*4 + c)*64 + lane)*8 + j] = W[c*16 + (lane&15)][s*32 + (lane>>4)*8 + j]
__global__ __launch_bounds__(256) void prep_w16_kernel(const float* __restrict__ W,
                                                       f16* __restrict__ wf) {
    int t = blockIdx.x * 256 + threadIdx.x;   // 0..4095
    int s = t >> 8;
    int c = (t >> 6) & 3;
    int l = t & 63;
    int row = c * 16 + (l & 15);
    int kb = s * 32 + ((l >> 4) << 3);
#pragma unroll
    for (int j = 0; j < 8; ++j)
        wf[(size_t)t * 8 + j] = (f16)W[row * F_IN + kb + j];
}

__global__ void zero_int_kernel(int* __restrict__ p, int n) {
    int i = blockIdx.x * blockDim.x + threadIdx.x;
    if (i < n) p[i] = 0;
}

__global__ __launch_bounds__(256) void hist_kernel(const int* __restrict__ row,
                                                   int* __restrict__ cnt, int n_edges) {
    int e = blockIdx.x * blockDim.x + threadIdx.x;
    if (e < n_edges) atomicAdd(&cnt[row[e]], 1);
}

__global__ __launch_bounds__(256) void scan1_kernel(const int* __restrict__ cnt,
                                                    int* __restrict__ scn,
                                                    int* __restrict__ partials, int n) {
    __shared__ int s[256];
    const int t = threadIdx.x;
    const int i = blockIdx.x * 256 + t;
    int v = (i < n) ? cnt[i] : 0;
    s[t] = v;
    __syncthreads();
#pragma unroll
    for (int off = 1; off < 256; off <<= 1) {
        int x = (t >= off) ? s[t - off] : 0;
        __syncthreads();
        s[t] += x;
        __syncthreads();
    }
    if (i < n) scn[i] = s[t] - v;
    if (t == 255) partials[blockIdx.x] = s[255];
}

__global__ __launch_bounds__(512) void scan2_kernel(const int* __restrict__ partials,
                                                    int* __restrict__ poff, int P) {
    __shared__ int s[512];
    const int t = threadIdx.x;
    int v = (t < P) ? partials[t] : 0;
    s[t] = v;
    __syncthreads();
#pragma unroll
    for (int off = 1; off < 512; off <<= 1) {
        int x = (t >= off) ? s[t - off] : 0;
        __syncthreads();
        s[t] += x;
        __syncthreads();
    }
    if (t < P) poff[t] = s[t] - v;
}

__global__ __launch_bounds__(256) void scan3_kernel(const int* __restrict__ scn,
                                                    const int* __restrict__ poff,
                                                    int* __restrict__ ptr,
                                                    int* __restrict__ cursor,
                                                    int n, int n_edges) {
    int i = blockIdx.x * 256 + threadIdx.x;
    if (i < n) {
        int p = scn[i] + poff[i >> 8];
        ptr[i] = p;
        cursor[i] = p;
    }
    if (i == 0) ptr[n] = n_edges;
}

__global__ __launch_bounds__(256) void fill_kernel(const int* __restrict__ row,
                                                   const int* __restrict__ col,
                                                   const float* __restrict__ w,
                                                   int* __restrict__ cursor,
                                                   int2* __restrict__ ecsr, int n_edges) {
    int e = blockIdx.x * blockDim.x + threadIdx.x;
    if (e >= n_edges) return;
    int p = atomicAdd(&cursor[row[e]], 1);
    ecsr[p] = make_int2(col[e], __float_as_int(w[e]));
}

// H16[n][j] = (f16) sum_k X[n][k]*W[j][k]. No LDS: A from global (4 lanes/line),
// B from pre-laid-out f16 fragments (L2-resident 64KB). 4 waves x 16 rows = 64-row tile.
__global__ __launch_bounds__(256) void gemm_mfma_kernel(const float* __restrict__ X,
                                                        const f16* __restrict__ wf,
                                                        f16* __restrict__ H,
                                                        int n_nodes) {
    const int lane = threadIdx.x & 63;
    const int w = threadIdx.x >> 6;
    const int m0 = blockIdx.x * 64 + w * 16;
    int arow = m0 + (lane & 15);
    if (arow >= n_nodes) arow = n_nodes - 1;          // clamp loads; stores guarded
    const float* xp = X + (size_t)arow * F_IN + ((lane >> 4) << 3);
    const f16x8* wfv = reinterpret_cast<const f16x8*>(wf);

    f32x4 acc0 = {}, acc1 = {}, acc2 = {}, acc3 = {};
    for (int s = 0; s < 16; ++s) {
        const f16x8* bp = wfv + (size_t)(s * 4) * 64 + lane;
        f16x8 b0 = bp[0];
        f16x8 b1 = bp[64];
        f16x8 b2 = bp[128];
        f16x8 b3 = bp[192];
        float4 xa = *reinterpret_cast<const float4*>(xp + s * 32);
        float4 xb = *reinterpret_cast<const float4*>(xp + s * 32 + 4);
        f16x8 a;
        a[0] = (f16)xa.x; a[1] = (f16)xa.y; a[2] = (f16)xa.z; a[3] = (f16)xa.w;
        a[4] = (f16)xb.x; a[5] = (f16)xb.y; a[6] = (f16)xb.z; a[7] = (f16)xb.w;
        acc0 = __builtin_amdgcn_mfma_f32_16x16x32_f16(a, b0, acc0, 0, 0, 0);
        acc1 = __builtin_amdgcn_mfma_f32_16x16x32_f16(a, b1, acc1, 0, 0, 0);
        acc2 = __builtin_amdgcn_mfma_f32_16x16x32_f16(a, b2, acc2, 0, 0, 0);
        acc3 = __builtin_amdgcn_mfma_f32_16x16x32_f16(a, b3, acc3, 0, 0, 0);
    }

    // C/D layout: row_in_tile = (lane>>4)*4 + j, col = lane&15
    const int col = lane & 15;
#pragma unroll
    for (int j = 0; j < 4; ++j) {
        int r = m0 + ((lane >> 4) << 2) + j;
        if (r < n_nodes) {
            f16* hp = H + (size_t)r * HDIM + col;
            hp[0]  = (f16)acc0[j];
            hp[16] = (f16)acc1[j];
            hp[32] = (f16)acc2[j];
            hp[48] = (f16)acc3[j];
        }
    }
}

// fused gather-aggregate + bias + PReLU + wsum-dot -> z[n]; one wave per node
__global__ __launch_bounds__(256) void agg_finalize_kernel(const int* __restrict__ ptr,
                                                           const int2* __restrict__ ecsr,
                                                           const f16* __restrict__ h,
                                                           const float* __restrict__ gbias,
                                                           const float* __restrict__ wsum,
                                                           const float* __restrict__ prelu_a,
                                                           float* __restrict__ z,
                                                           int n_nodes) {
    const int lane = threadIdx.x & 63;
    const int wv = threadIdx.x >> 6;
    const int n = blockIdx.x * 4 + wv;
    if (n >= n_nodes) return;
    const int p0 = __builtin_amdgcn_readfirstlane(ptr[n]);
    const int p1 = __builtin_amdgcn_readfirstlane(ptr[n + 1]);
    float acc = 0.f;
    int i = p0;
    for (; i + 1 < p1; i += 2) {
        int2 e0 = ecsr[i];
        int2 e1 = ecsr[i + 1];
        float h0 = (float)h[(size_t)e0.x * HDIM + lane];
        float h1 = (float)h[(size_t)e1.x * HDIM + lane];
        acc = fmaf(__int_as_float(e0.y), h0, acc);
        acc = fmaf(__int_as_float(e1.y), h1, acc);
    }
    if (i < p1) {
        int2 e0 = ecsr[i];
        acc = fmaf(__int_as_float(e0.y), (float)h[(size_t)e0.x * HDIM + lane], acc);
    }
    float v = acc + gbias[lane];
    const float a = prelu_a[0];
    v = (v >= 0.f) ? v : a * v;
    float p = v * wsum[lane];
#pragma unroll
    for (int m = 32; m >= 1; m >>= 1) p += __shfl_xor(p, m, 64);
    if (lane == 0) z[n] = p + wsum[HDIM];
}

extern "C" void kernel_launch(void* const* d_in, const int* in_sizes, int n_in,
                              void* d_out, int out_size, void* d_ws, size_t ws_size,
                              hipStream_t stream) {
    const float* x1    = (const float*)d_in[0];
    const float* x2    = (const float*)d_in[1];
    const int*   erow  = (const int*)d_in[2];
    const int*   ecol  = (const int*)d_in[3];
    const float* ew    = (const float*)d_in[4];
    const float* fcw   = (const float*)d_in[5];
    const float* gbias = (const float*)d_in[6];
    const float* pa    = (const float*)d_in[7];
    const float* linw  = (const float*)d_in[8];
    const float* linb  = (const float*)d_in[9];
    float* out = (float*)d_out;

    const int n_nodes = in_sizes[0] / F_IN;   // 100000
    const int n_edges = in_sizes[2];          // 1600000
    const int NB1 = (n_nodes + 255) / 256;

    // workspace layout
    f16*   h16    = (f16*)d_ws;                                 // n_nodes*64 f16
    f16*   wf     = h16 + (size_t)n_nodes * HDIM;               // 64*512 f16 (frag order)
    int2*  ecsr   = (int2*)(wf + 64 * F_IN);                    // n_edges int2
    int*   cnt    = (int*)(ecsr + n_edges);                     // n_nodes
    int*   scn    = cnt + n_nodes;                              // n_nodes
    int*   ptr    = scn + n_nodes;                              // n_nodes+1
    int*   cursor = ptr + n_nodes + 1;                          // n_nodes
    int*   partials = cursor + n_nodes;                         // NB1
    int*   poff   = partials + NB1;                             // NB1
    float* wsum   = (float*)(poff + NB1);                       // 65 f32

    const int gN   = (n_nodes + 255) / 256;
    const int gE   = (n_edges + 255) / 256;
    const int gemm_grid = (n_nodes + 63) / 64;
    const int fin_grid  = (n_nodes + 3) / 4;

    prep_kernel<<<1, 64, 0, stream>>>(linw, linb, wsum);
    prep_w16_kernel<<<16, 256, 0, stream>>>(fcw, wf);

    // CSR build (shared by both inputs)
    zero_int_kernel<<<gN, 256, 0, stream>>>(cnt, n_nodes);
    hist_kernel<<<gE, 256, 0, stream>>>(erow, cnt, n_edges);
    scan1_kernel<<<NB1, 256, 0, stream>>>(cnt, scn, partials, n_nodes);
    scan2_kernel<<<1, 512, 0, stream>>>(partials, poff, NB1);
    scan3_kernel<<<gN, 256, 0, stream>>>(scn, poff, ptr, cursor, n_nodes, n_edges);
    fill_kernel<<<gE, 256, 0, stream>>>(erow, ecol, ew, cursor, ecsr, n_edges);

    const float* xs[2] = {x1, x2};
    for (int s = 0; s < 2; ++s) {
        gemm_mfma_kernel<<<gemm_grid, 256, 0, stream>>>(xs[s], wf, h16, n_nodes);
        agg_finalize_kernel<<<fin_grid, 256, 0, stream>>>(ptr, ecsr, h16, gbias, wsum, pa,
                                                          out + (size_t)s * n_nodes, n_nodes);
    }
}